// Round 7
// baseline (231.788 us; speedup 1.0000x reference)
//
#include <hip/hip_runtime.h>
#include <hip/hip_bf16.h>
#include <math.h>

typedef __bf16 bf16;
typedef __bf16 bf16x4 __attribute__((ext_vector_type(4)));
typedef __bf16 bf16x8 __attribute__((ext_vector_type(8)));
typedef float f32x4 __attribute__((ext_vector_type(4)));
typedef unsigned int u32;

#define LOG2E 1.44269504f

__device__ inline float fast_exp2(float x) {
#if __has_builtin(__builtin_amdgcn_exp2f)
    return __builtin_amdgcn_exp2f(x);
#else
    return exp2f(x);
#endif
}

// async global->LDS, 16B per lane; LDS dest must be lane-contiguous (tid*16B)
#define GL2LDS(gp, lp) __builtin_amdgcn_global_load_lds( \
    (const __attribute__((address_space(1))) u32*)(gp),  \
    (__attribute__((address_space(3))) u32*)(lp), 16, 0, 0)

// Problem constants: B=64, ORDER=2, S=256, D=256, H=8, HD=32

// ---------------- kernel 1 (fused prologue): xb = bf16(x); Wt; A bitmasks ------
__global__ void prep_k(const float* __restrict__ x, const float* __restrict__ Wp,
                       const int* __restrict__ A, bf16* __restrict__ xb,
                       bf16* __restrict__ Wt, unsigned* __restrict__ m1,
                       unsigned* __restrict__ m2) {
    int bid = blockIdx.x;
    int tid = threadIdx.x;
    if (bid < 4096) {
        int gid = bid * 256 + tid;              // 1,048,576 groups of 8
        const f32x4* xp = (const f32x4*)x + (size_t)gid * 2;
        f32x4 a = xp[0], b4 = xp[1];
        bf16x8 o;
#pragma unroll
        for (int c = 0; c < 4; ++c) { o[c] = (bf16)a[c]; o[c + 4] = (bf16)b4[c]; }
        ((bf16x8*)xb)[gid] = o;
    } else if (bid < 5120) {
        int gid = (bid - 4096) * 256 + tid;     // 4*256*256 elements
        int k = gid & 255;
        int n = (gid >> 8) & 255;
        int ij = gid >> 16;
        Wt[gid] = (bf16)Wp[(ij * 256 + k) * 256 + n];
    } else {
        int pb = bid - 5120;                    // 256 = ijb*2 + s-half
        int sh = pb & 1;
        int ijb = pb >> 1;                      // b*2+i
        const int* Ab = A + ((size_t)ijb << 16);
        unsigned w1 = 0, w2 = 0;
#pragma unroll 8
        for (int sl = 0; sl < 128; ++sl) {
            int s = sh * 128 + sl;
            int av = Ab[s * 256 + tid];
            unsigned f1 = (av == 2 || av == 4) ? 1u : 0u;
            unsigned f2 = (av == 3 || av == 4) ? 1u : 0u;
            w1 |= f1 << (s & 31);
            w2 |= f2 << (s & 31);
            if ((s & 31) == 31) {
                int kc = s >> 5;
                m1[(ijb * 8 + kc) * 256 + tid] = w1;
                m2[(ijb * 8 + kc) * 256 + tid] = w2;
                w1 = 0; w2 = 0;
            }
        }
    }
}

// ---------------- kernel 2: transposed projection GEMM + register scores ------
// D[d][s] = (x@W+b)^T via swapped MFMA operands; Vt [ijb][h][d][s] via TL;
// a_s/a_d computed from acc REGISTERS (no LDS dot), quad-reduced by shfl.
__launch_bounds__(256)
__global__ void proj_gemm(const bf16* __restrict__ xb, const bf16* __restrict__ Wt,
                          const float* __restrict__ bp, const float* __restrict__ att_src,
                          const float* __restrict__ att_dst, bf16* __restrict__ Vt,
                          float* __restrict__ asb, float* __restrict__ adb) {
    __shared__ char smem[35840 + 1024];
    bf16* As = (bf16*)smem;            // x tile  [s 128][k 32], contiguous
    bf16* Bs = (bf16*)(smem + 8192);   // Wt tile [d 128][k 32]
    bf16* TL = (bf16*)smem;            // epilogue overlay: [d 128][s stride 140]
    float* attL = (float*)(smem + 35840);   // [which 2][dloc 128]

    int tid = threadIdx.x;
    int mt = blockIdx.x, nt = blockIdx.y, i = blockIdx.z;
    int n0 = nt * 128;
    int j = n0 >> 8, d0 = n0 & 255;
    int ij = i * 2 + j;
    int m0 = mt * 128;
    int b = m0 >> 8, shalf = (m0 >> 7) & 1;

    // preload att vectors for this block's 4 heads: attL[which][dloc]
    {
        int which = tid >> 7, rest = tid & 127;
        const float* ap = which ? att_dst : att_src;
        attL[tid] = ap[(ij * 8 + (d0 >> 5) + (rest >> 5)) * 32 + (rest & 31)];
    }

    // staging: chunk c -> row c>>2, k-offset (c&3)*8 ; LDS dest = c*16B
    int c0 = tid, c1 = tid + 256;
    int r0 = c0 >> 2, k80 = (c0 & 3) * 8;
    int r1 = c1 >> 2, k81 = (c1 & 3) * 8;
    const bf16* ga0 = xb + (((size_t)((b * 2 + i) * 256 + shalf * 128 + r0)) << 8) + k80;
    const bf16* ga1 = xb + (((size_t)((b * 2 + i) * 256 + shalf * 128 + r1)) << 8) + k81;
    const bf16* gb0 = Wt + (((size_t)(ij * 256 + d0 + r0)) << 8) + k80;
    const bf16* gb1 = Wt + (((size_t)(ij * 256 + d0 + r1)) << 8) + k81;
    bf16* la0 = As + c0 * 8;
    bf16* la1 = As + c1 * 8;
    bf16* lb0 = Bs + c0 * 8;
    bf16* lb1 = Bs + c1 * 8;

    int wave = tid >> 6, lane = tid & 63;
    int wd = (wave & 1) * 64, ws = (wave >> 1) * 64;
    int lrow = lane & 15, quad = lane >> 4;

    f32x4 acc[4][4];   // [dj][sj]
#pragma unroll
    for (int a = 0; a < 4; ++a)
#pragma unroll
        for (int c = 0; c < 4; ++c) acc[a][c] = (f32x4){0.f, 0.f, 0.f, 0.f};

    for (int kc = 0; kc < 8; ++kc) {
        int k0 = kc * 32;
        GL2LDS(ga0 + k0, la0);
        GL2LDS(ga1 + k0, la1);
        GL2LDS(gb0 + k0, lb0);
        GL2LDS(gb1 + k0, lb1);
        __syncthreads();
        bf16x8 wf[4], xf[4];
#pragma unroll
        for (int dj = 0; dj < 4; ++dj)
            wf[dj] = *(const bf16x8*)&Bs[(wd + dj * 16 + lrow) * 32 + quad * 8];
#pragma unroll
        for (int sj = 0; sj < 4; ++sj)
            xf[sj] = *(const bf16x8*)&As[(ws + sj * 16 + lrow) * 32 + quad * 8];
#pragma unroll
        for (int dj = 0; dj < 4; ++dj)
#pragma unroll
            for (int sj = 0; sj < 4; ++sj)
                acc[dj][sj] = __builtin_amdgcn_mfma_f32_16x16x32_bf16(wf[dj], xf[sj], acc[dj][sj], 0, 0, 0);
        __syncthreads();
    }

    // ---- bias + cvt -> TL[d][s] AND register score partials ----
    float sc[2][2][4];   // [which][head-half][sj]
#pragma unroll
    for (int w2 = 0; w2 < 2; ++w2)
#pragma unroll
        for (int hf = 0; hf < 2; ++hf)
#pragma unroll
            for (int sj = 0; sj < 4; ++sj) sc[w2][hf][sj] = 0.f;
#pragma unroll
    for (int dj = 0; dj < 4; ++dj) {
        int hf = dj >> 1;
#pragma unroll
        for (int r = 0; r < 4; ++r) {
            int dl = wd + dj * 16 + quad * 4 + r;
            float bias = bp[ij * 256 + d0 + dl];
            float avs = attL[dl];
            float avd = attL[128 + dl];
#pragma unroll
            for (int sj = 0; sj < 4; ++sj) {
                float v = acc[dj][sj][r] + bias;
                TL[dl * 140 + ws + sj * 16 + lrow] = (bf16)v;
                sc[0][hf][sj] += v * avs;
                sc[1][hf][sj] += v * avd;
            }
        }
    }
    // quad-reduce the score partials (d-range of a head spans the 4 quads)
#pragma unroll
    for (int w2 = 0; w2 < 2; ++w2)
#pragma unroll
        for (int hf = 0; hf < 2; ++hf)
#pragma unroll
            for (int sj = 0; sj < 4; ++sj) {
                float v = sc[w2][hf][sj];
                v += __shfl_xor(v, 16, 64);
                v += __shfl_xor(v, 32, 64);
                sc[w2][hf][sj] = v;
            }
    if (lane < 16) {
        int hbase = (d0 >> 5) + (wd >> 5);   // wd>>5 in {0,2}
#pragma unroll
        for (int w2 = 0; w2 < 2; ++w2) {
            float* outp = w2 ? adb : asb;
#pragma unroll
            for (int hf = 0; hf < 2; ++hf) {
                int hh = hbase + hf;
#pragma unroll
                for (int sj = 0; sj < 4; ++sj) {
                    int s = ws + sj * 16 + lane;
                    outp[((ij * 64 + b) * 8 + hh) * 256 + shalf * 128 + s] = sc[w2][hf][sj] * LOG2E;
                }
            }
        }
    }
    __syncthreads();

    // ---- Vt store: thread -> (dl = tid>>1, s-half 64) ----
    {
        int dl = tid >> 1, sh64 = (tid & 1) * 64;
        const bf16* src = TL + dl * 140 + sh64;
        bf16* dst = Vt + (((size_t)(ij * 64 + b)) << 16) + (size_t)(d0 + dl) * 256
                    + shalf * 128 + sh64;   // slab per (ij,b) = 8h*32d*256s = <<16
#pragma unroll
        for (int q = 0; q < 16; ++q)
            *(bf16x4*)(dst + q * 4) = *(const bf16x4*)(src + q * 4);
    }
}

// ---------------- kernel 3: fused attention + order-mean + PReLU ---------------
// grid 1024: (b, head-group of 4, t-tile of 32); block owns both orders + convs.
__launch_bounds__(256, 3)
__global__ void attn_k(const bf16* __restrict__ Vt, const unsigned* __restrict__ m1,
                       const unsigned* __restrict__ m2, const float* __restrict__ asb,
                       const float* __restrict__ adb, const float* __restrict__ gbias,
                       const float* __restrict__ prelu_a, float* __restrict__ out) {
    int bid = blockIdx.x;
    int tt = bid & 7, hg = (bid >> 3) & 1, b = bid >> 4;
    int t0 = tt * 32;
    int tid = threadIdx.x, wave = tid >> 6, lane = tid & 63;
    int lrow = lane & 15, quad = lane >> 4;
    int h = hg * 4 + wave;

    __shared__ float    as_l[2][2][4][256];   // [i][conv][wave-head][s]   16 KB
    __shared__ unsigned ml[2][2][8][32];      // [i][conv][kc][t_local]     4 KB
    __shared__ float    l_lds[2][2][4][32];   // [i][conv][wave-head][tl]   2 KB

#pragma unroll
    for (int p = 0; p < 16; ++p) {
        int idx = p * 256 + tid;
        int i = idx >> 11, c = (idx >> 10) & 1, w = (idx >> 8) & 3, s = idx & 255;
        as_l[i][c][w][s] = asb[(((i * 2 + c) * 64 + b) * 8 + hg * 4 + w) * 256 + s];
    }
#pragma unroll
    for (int p = 0; p < 4; ++p) {
        int idx = p * 256 + tid;            // 1024 mask words
        int i = idx >> 9, c = (idx >> 8) & 1, kc = (idx >> 5) & 7, tl = idx & 31;
        ml[i][c][kc][tl] = (c ? m2 : m1)[((b * 2 + i) * 8 + kc) * 256 + t0 + tl];
    }
    float ad_r[2][2][2];
#pragma unroll
    for (int i = 0; i < 2; ++i)
#pragma unroll
        for (int c = 0; c < 2; ++c)
#pragma unroll
            for (int mi = 0; mi < 2; ++mi)
                ad_r[i][c][mi] = adb[(((i * 2 + c) * 64 + b) * 8 + h) * 256 + t0 + mi * 16 + lrow];
    __syncthreads();

    const bf16* vtp[2][2];
#pragma unroll
    for (int i = 0; i < 2; ++i)
#pragma unroll
        for (int c = 0; c < 2; ++c)
            vtp[i][c] = Vt + (((size_t)(((i * 2 + c) * 64 + b) * 8 + h)) << 13);

    f32x4 acc[2][2][2][2];
#pragma unroll
    for (int i = 0; i < 2; ++i)
#pragma unroll
        for (int c = 0; c < 2; ++c)
#pragma unroll
            for (int mi = 0; mi < 2; ++mi)
#pragma unroll
                for (int ni = 0; ni < 2; ++ni) acc[i][c][mi][ni] = (f32x4){0.f, 0.f, 0.f, 0.f};
    float lsum[2][2][2];
#pragma unroll
    for (int i = 0; i < 2; ++i)
#pragma unroll
        for (int c = 0; c < 2; ++c)
#pragma unroll
            for (int mi = 0; mi < 2; ++mi) lsum[i][c][mi] = 0.f;

    for (int kc = 0; kc < 8; ++kc) {
        int s0 = kc * 32;
        // ---- V b-frags: one b128 load each (Vt is [d][s]) ----
        bf16x8 bfr[2][2][2];
#pragma unroll
        for (int i = 0; i < 2; ++i)
#pragma unroll
            for (int c = 0; c < 2; ++c)
#pragma unroll
                for (int ni = 0; ni < 2; ++ni)
                    bfr[i][c][ni] = *(const bf16x8*)(vtp[i][c] + (size_t)(ni * 16 + lrow) * 256 + s0 + quad * 8);
#pragma unroll
        for (int i = 0; i < 2; ++i) {
#pragma unroll
            for (int c = 0; c < 2; ++c) {
                f32x4 asv0 = *(const f32x4*)&as_l[i][c][wave][s0 + quad * 8];
                f32x4 asv1 = *(const f32x4*)&as_l[i][c][wave][s0 + quad * 8 + 4];
#pragma unroll
                for (int mi = 0; mi < 2; ++mi) {
                    unsigned wb = ml[i][c][kc][mi * 16 + lrow] >> (quad * 8);
                    float ad = ad_r[i][c][mi];
                    bf16x8 af;
#pragma unroll
                    for (int j = 0; j < 8; ++j) {
                        float u = (j < 4 ? asv0[j] : asv1[j - 4]) + ad;
                        u = fmaxf(u, 0.2f * u);           // leaky_relu (log2 domain)
                        u = ((wb >> j) & 1u) ? u : 0.f;   // masked -> exp2(0)=1
                        float e = fast_exp2(u);
                        lsum[i][c][mi] += e;
                        af[j] = (bf16)e;
                    }
                    acc[i][c][mi][0] = __builtin_amdgcn_mfma_f32_16x16x32_bf16(af, bfr[i][c][0], acc[i][c][mi][0], 0, 0, 0);
                    acc[i][c][mi][1] = __builtin_amdgcn_mfma_f32_16x16x32_bf16(af, bfr[i][c][1], acc[i][c][mi][1], 0, 0, 0);
                }
            }
        }
    }

    // ---- complete row sums across quads ----
#pragma unroll
    for (int i = 0; i < 2; ++i)
#pragma unroll
        for (int c = 0; c < 2; ++c)
#pragma unroll
            for (int mi = 0; mi < 2; ++mi) {
                float l = lsum[i][c][mi];
                l += __shfl_xor(l, 16, 64);
                l += __shfl_xor(l, 32, 64);
                if (lane < 16) l_lds[i][c][wave][mi * 16 + lane] = l;
            }
    __syncthreads();

    // ---- epilogue: normalize+residual+gbias per order, then mean+PReLU --------
#pragma unroll
    for (int ni = 0; ni < 2; ++ni) {
        int dcol = h * 32 + ni * 16 + lrow;
        float gb0 = gbias[0 * 256 + dcol] + gbias[1 * 256 + dcol];   // order 0
        float gb1 = gbias[2 * 256 + dcol] + gbias[3 * 256 + dcol];   // order 1
        float pa = prelu_a[dcol];
        const bf16* r00 = vtp[0][0] + (size_t)(ni * 16 + lrow) * 256 + t0;
        const bf16* r01 = vtp[0][1] + (size_t)(ni * 16 + lrow) * 256 + t0;
        const bf16* r10 = vtp[1][0] + (size_t)(ni * 16 + lrow) * 256 + t0;
        const bf16* r11 = vtp[1][1] + (size_t)(ni * 16 + lrow) * 256 + t0;
#pragma unroll
        for (int mi = 0; mi < 2; ++mi) {
            bf16x4 rv00 = *(const bf16x4*)(r00 + mi * 16 + quad * 4);
            bf16x4 rv01 = *(const bf16x4*)(r01 + mi * 16 + quad * 4);
            bf16x4 rv10 = *(const bf16x4*)(r10 + mi * 16 + quad * 4);
            bf16x4 rv11 = *(const bf16x4*)(r11 + mi * 16 + quad * 4);
#pragma unroll
            for (int r = 0; r < 4; ++r) {
                int tl = mi * 16 + quad * 4 + r;
                int t = t0 + tl;
                float v0 = acc[0][0][mi][ni][r] * __builtin_amdgcn_rcpf(l_lds[0][0][wave][tl])
                         + acc[0][1][mi][ni][r] * __builtin_amdgcn_rcpf(l_lds[0][1][wave][tl])
                         + (float)rv00[r] + (float)rv01[r] + gb0;
                float v1 = acc[1][0][mi][ni][r] * __builtin_amdgcn_rcpf(l_lds[1][0][wave][tl])
                         + acc[1][1][mi][ni][r] * __builtin_amdgcn_rcpf(l_lds[1][1][wave][tl])
                         + (float)rv10[r] + (float)rv11[r] + gb1;
                float mn = 0.5f * (v0 + v1);
                float a0 = v0 + mn, a1 = v1 + mn;
                a0 = a0 >= 0.f ? a0 : pa * a0;
                a1 = a1 >= 0.f ? a1 : pa * a1;
                out[(((size_t)((b * 2 + 0) * 256 + t)) << 8) + dcol] = a0;
                out[(((size_t)((b * 2 + 1) * 256 + t)) << 8) + dcol] = a1;
            }
        }
    }
}

extern "C" void kernel_launch(void* const* d_in, const int* in_sizes, int n_in,
                              void* d_out, int out_size, void* d_ws, size_t ws_size,
                              hipStream_t stream) {
    const float* x       = (const float*)d_in[0];
    const int*   A       = (const int*)d_in[1];
    const float* Wp      = (const float*)d_in[2];
    const float* bp      = (const float*)d_in[3];
    const float* att_src = (const float*)d_in[4];
    const float* att_dst = (const float*)d_in[5];
    const float* gbias   = (const float*)d_in[6];
    const float* prelu_a = (const float*)d_in[7];
    float* out = (float*)d_out;

    char* ws = (char*)d_ws;
    bf16*     Wt  = (bf16*)ws;                            //   524288 B
    unsigned* m1  = (unsigned*)(ws + 524288);             //  1048576 B
    unsigned* m2  = (unsigned*)(ws + 1572864);            //  1048576 B
    float*    asb = (float*)(ws + 2621440);               //  2097152 B
    float*    adb = (float*)(ws + 4718592);               //  2097152 B
    bf16*     xb  = (bf16*)(ws + 6815744);                // 16777216 B
    bf16*     Vt  = (bf16*)(ws + 23592960);               // 16777216 B

    prep_k<<<5376, 256, 0, stream>>>(x, Wp, A, xb, Wt, m1, m2);
    dim3 gproj(128, 4, 2);
    proj_gemm<<<gproj, 256, 0, stream>>>(xb, Wt, bp, att_src, att_dst, Vt, asb, adb);
    attn_k<<<1024, 256, 0, stream>>>(Vt, m1, m2, asb, adb, gbias, prelu_a, out);
}

// Round 8
// 211.178 us; speedup vs baseline: 1.0976x; 1.0976x over previous
//
#include <hip/hip_runtime.h>
#include <hip/hip_bf16.h>
#include <math.h>

typedef __bf16 bf16;
typedef __bf16 bf16x4 __attribute__((ext_vector_type(4)));
typedef __bf16 bf16x8 __attribute__((ext_vector_type(8)));
typedef float f32x4 __attribute__((ext_vector_type(4)));
typedef unsigned int u32;

#define LOG2E 1.44269504f

__device__ inline float fast_exp2(float x) {
#if __has_builtin(__builtin_amdgcn_exp2f)
    return __builtin_amdgcn_exp2f(x);
#else
    return exp2f(x);
#endif
}

// async global->LDS, 16B per lane; LDS dest must be lane-contiguous (tid*16B)
#define GL2LDS(gp, lp) __builtin_amdgcn_global_load_lds( \
    (const __attribute__((address_space(1))) u32*)(gp),  \
    (__attribute__((address_space(3))) u32*)(lp), 16, 0, 0)

// Problem constants: B=64, ORDER=2, S=256, D=256, H=8, HD=32

// ---------------- kernel 1 (fused prologue): xb = bf16(x); Wt; A bitmasks ------
__global__ void prep_k(const float* __restrict__ x, const float* __restrict__ Wp,
                       const int* __restrict__ A, bf16* __restrict__ xb,
                       bf16* __restrict__ Wt, unsigned* __restrict__ m1,
                       unsigned* __restrict__ m2) {
    int bid = blockIdx.x;
    int tid = threadIdx.x;
    if (bid < 4096) {
        int gid = bid * 256 + tid;              // 1,048,576 groups of 8
        const f32x4* xp = (const f32x4*)x + (size_t)gid * 2;
        f32x4 a = xp[0], b4 = xp[1];
        bf16x8 o;
#pragma unroll
        for (int c = 0; c < 4; ++c) { o[c] = (bf16)a[c]; o[c + 4] = (bf16)b4[c]; }
        ((bf16x8*)xb)[gid] = o;
    } else if (bid < 5120) {
        int gid = (bid - 4096) * 256 + tid;     // 4*256*256 elements
        int k = gid & 255;
        int n = (gid >> 8) & 255;
        int ij = gid >> 16;
        Wt[gid] = (bf16)Wp[(ij * 256 + k) * 256 + n];
    } else {
        int pb = bid - 5120;                    // 256 = ijb*2 + s-half
        int sh = pb & 1;
        int ijb = pb >> 1;                      // b*2+i
        const int* Ab = A + ((size_t)ijb << 16);
        unsigned w1 = 0, w2 = 0;
#pragma unroll 8
        for (int sl = 0; sl < 128; ++sl) {
            int s = sh * 128 + sl;
            int av = Ab[s * 256 + tid];
            unsigned f1 = (av == 2 || av == 4) ? 1u : 0u;
            unsigned f2 = (av == 3 || av == 4) ? 1u : 0u;
            w1 |= f1 << (s & 31);
            w2 |= f2 << (s & 31);
            if ((s & 31) == 31) {
                int kc = s >> 5;
                m1[(ijb * 8 + kc) * 256 + tid] = w1;
                m2[(ijb * 8 + kc) * 256 + tid] = w2;
                w1 = 0; w2 = 0;
            }
        }
    }
}

// ---------------- kernel 2: transposed projection GEMM + register scores ------
// D[d][s] = (x@W+b)^T via swapped MFMA operands; Vt [ijb][h][d][s] via TL;
// a_s/a_d computed from acc REGISTERS (no LDS dot), quad-reduced by shfl.
__launch_bounds__(256)
__global__ void proj_gemm(const bf16* __restrict__ xb, const bf16* __restrict__ Wt,
                          const float* __restrict__ bp, const float* __restrict__ att_src,
                          const float* __restrict__ att_dst, bf16* __restrict__ Vt,
                          float* __restrict__ asb, float* __restrict__ adb) {
    __shared__ char smem[35840 + 1024];
    bf16* As = (bf16*)smem;            // x tile  [s 128][k 32], contiguous
    bf16* Bs = (bf16*)(smem + 8192);   // Wt tile [d 128][k 32]
    bf16* TL = (bf16*)smem;            // epilogue overlay: [d 128][s stride 140]
    float* attL = (float*)(smem + 35840);   // [which 2][dloc 128]

    int tid = threadIdx.x;
    int mt = blockIdx.x, nt = blockIdx.y, i = blockIdx.z;
    int n0 = nt * 128;
    int j = n0 >> 8, d0 = n0 & 255;
    int ij = i * 2 + j;
    int m0 = mt * 128;
    int b = m0 >> 8, shalf = (m0 >> 7) & 1;

    // preload att vectors for this block's 4 heads: attL[which][dloc]
    {
        int which = tid >> 7, rest = tid & 127;
        const float* ap = which ? att_dst : att_src;
        attL[tid] = ap[(ij * 8 + (d0 >> 5) + (rest >> 5)) * 32 + (rest & 31)];
    }

    // staging: chunk c -> row c>>2, k-offset (c&3)*8 ; LDS dest = c*16B
    int c0 = tid, c1 = tid + 256;
    int r0 = c0 >> 2, k80 = (c0 & 3) * 8;
    int r1 = c1 >> 2, k81 = (c1 & 3) * 8;
    const bf16* ga0 = xb + (((size_t)((b * 2 + i) * 256 + shalf * 128 + r0)) << 8) + k80;
    const bf16* ga1 = xb + (((size_t)((b * 2 + i) * 256 + shalf * 128 + r1)) << 8) + k81;
    const bf16* gb0 = Wt + (((size_t)(ij * 256 + d0 + r0)) << 8) + k80;
    const bf16* gb1 = Wt + (((size_t)(ij * 256 + d0 + r1)) << 8) + k81;
    bf16* la0 = As + c0 * 8;
    bf16* la1 = As + c1 * 8;
    bf16* lb0 = Bs + c0 * 8;
    bf16* lb1 = Bs + c1 * 8;

    int wave = tid >> 6, lane = tid & 63;
    int wd = (wave & 1) * 64, ws = (wave >> 1) * 64;
    int lrow = lane & 15, quad = lane >> 4;

    f32x4 acc[4][4];   // [dj][sj]
#pragma unroll
    for (int a = 0; a < 4; ++a)
#pragma unroll
        for (int c = 0; c < 4; ++c) acc[a][c] = (f32x4){0.f, 0.f, 0.f, 0.f};

    for (int kc = 0; kc < 8; ++kc) {
        int k0 = kc * 32;
        GL2LDS(ga0 + k0, la0);
        GL2LDS(ga1 + k0, la1);
        GL2LDS(gb0 + k0, lb0);
        GL2LDS(gb1 + k0, lb1);
        __syncthreads();
        bf16x8 wf[4], xf[4];
#pragma unroll
        for (int dj = 0; dj < 4; ++dj)
            wf[dj] = *(const bf16x8*)&Bs[(wd + dj * 16 + lrow) * 32 + quad * 8];
#pragma unroll
        for (int sj = 0; sj < 4; ++sj)
            xf[sj] = *(const bf16x8*)&As[(ws + sj * 16 + lrow) * 32 + quad * 8];
#pragma unroll
        for (int dj = 0; dj < 4; ++dj)
#pragma unroll
            for (int sj = 0; sj < 4; ++sj)
                acc[dj][sj] = __builtin_amdgcn_mfma_f32_16x16x32_bf16(wf[dj], xf[sj], acc[dj][sj], 0, 0, 0);
        __syncthreads();
    }

    // ---- bias + cvt -> TL[d][s] AND register score partials ----
    float sc[2][2][4];   // [which][head-half][sj]
#pragma unroll
    for (int w2 = 0; w2 < 2; ++w2)
#pragma unroll
        for (int hf = 0; hf < 2; ++hf)
#pragma unroll
            for (int sj = 0; sj < 4; ++sj) sc[w2][hf][sj] = 0.f;
#pragma unroll
    for (int dj = 0; dj < 4; ++dj) {
        int hf = dj >> 1;
#pragma unroll
        for (int r = 0; r < 4; ++r) {
            int dl = wd + dj * 16 + quad * 4 + r;
            float bias = bp[ij * 256 + d0 + dl];
            float avs = attL[dl];
            float avd = attL[128 + dl];
#pragma unroll
            for (int sj = 0; sj < 4; ++sj) {
                float v = acc[dj][sj][r] + bias;
                TL[dl * 140 + ws + sj * 16 + lrow] = (bf16)v;
                sc[0][hf][sj] += v * avs;
                sc[1][hf][sj] += v * avd;
            }
        }
    }
    // quad-reduce the score partials (d-range of a head spans the 4 quads)
#pragma unroll
    for (int w2 = 0; w2 < 2; ++w2)
#pragma unroll
        for (int hf = 0; hf < 2; ++hf)
#pragma unroll
            for (int sj = 0; sj < 4; ++sj) {
                float v = sc[w2][hf][sj];
                v += __shfl_xor(v, 16, 64);
                v += __shfl_xor(v, 32, 64);
                sc[w2][hf][sj] = v;
            }
    if (lane < 16) {
        int hbase = (d0 >> 5) + (wd >> 5);   // wd>>5 in {0,2}
#pragma unroll
        for (int w2 = 0; w2 < 2; ++w2) {
            float* outp = w2 ? adb : asb;
#pragma unroll
            for (int hf = 0; hf < 2; ++hf) {
                int hh = hbase + hf;
#pragma unroll
                for (int sj = 0; sj < 4; ++sj) {
                    int s = ws + sj * 16 + lane;
                    outp[((ij * 64 + b) * 8 + hh) * 256 + shalf * 128 + s] = sc[w2][hf][sj] * LOG2E;
                }
            }
        }
    }
    __syncthreads();

    // ---- Vt store: thread -> (dl = tid>>1, s-half 64) ----
    {
        int dl = tid >> 1, sh64 = (tid & 1) * 64;
        const bf16* src = TL + dl * 140 + sh64;
        bf16* dst = Vt + (((size_t)(ij * 64 + b)) << 16) + (size_t)(d0 + dl) * 256
                    + shalf * 128 + sh64;   // slab per (ij,b) = 8h*32d*256s = <<16
#pragma unroll
        for (int q = 0; q < 16; ++q)
            *(bf16x4*)(dst + q * 4) = *(const bf16x4*)(src + q * 4);
    }
}

// ---------------- kernel 3: fused attention + order-mean + PReLU ---------------
// grid 512: (b, head-group of 4, t-tile of 64); block owns BOTH orders + convs.
// XCD swizzle: low 3 bits of bid = b%8, so all 8 tiles of a batch share an XCD
// (L2 working set per XCD = 8 b x 512 KB = 4 MB = one XCD L2).
__launch_bounds__(256, 2)
__global__ void attn_k(const bf16* __restrict__ Vt, const unsigned* __restrict__ m1,
                       const unsigned* __restrict__ m2, const float* __restrict__ asb,
                       const float* __restrict__ adb, const float* __restrict__ gbias,
                       const float* __restrict__ prelu_a, float* __restrict__ out) {
    int bid = blockIdx.x;
    int g = bid >> 3;                       // 64 groups
    int tt = g & 3, hg = (g >> 2) & 1;
    int b = (g >> 3) * 8 + (bid & 7);       // b%8 == bid%8 -> XCD locality
    int t0 = tt * 64;
    int tid = threadIdx.x, wave = tid >> 6, lane = tid & 63;
    int lrow = lane & 15, quad = lane >> 4;
    int h = hg * 4 + wave;

    __shared__ float    as_l[2][2][4][256];   // [i][conv][wave-head][s]   16 KB
    __shared__ unsigned ml[2][2][8][64];      // [i][conv][kc][t_local]     8 KB
    __shared__ float    l_lds[2][2][4][64];   // [i][conv][wave-head][tl]   4 KB

#pragma unroll
    for (int p = 0; p < 16; ++p) {
        int idx = p * 256 + tid;
        int i = idx >> 11, c = (idx >> 10) & 1, w = (idx >> 8) & 3, s = idx & 255;
        as_l[i][c][w][s] = asb[(((i * 2 + c) * 64 + b) * 8 + hg * 4 + w) * 256 + s];
    }
#pragma unroll
    for (int p = 0; p < 8; ++p) {
        int idx = p * 256 + tid;
        int i = idx >> 10, c = (idx >> 9) & 1, kc = (idx >> 6) & 7, tl = idx & 63;
        ml[i][c][kc][tl] = (c ? m2 : m1)[((b * 2 + i) * 8 + kc) * 256 + t0 + tl];
    }
    float ad_r[2][2][4];
#pragma unroll
    for (int i = 0; i < 2; ++i)
#pragma unroll
        for (int c = 0; c < 2; ++c)
#pragma unroll
            for (int mi = 0; mi < 4; ++mi)
                ad_r[i][c][mi] = adb[(((i * 2 + c) * 64 + b) * 8 + h) * 256 + t0 + mi * 16 + lrow];
    __syncthreads();

    const bf16* vtp[2][2];
#pragma unroll
    for (int i = 0; i < 2; ++i)
#pragma unroll
        for (int c = 0; c < 2; ++c)
            vtp[i][c] = Vt + (((size_t)(((i * 2 + c) * 64 + b) * 8 + h)) << 13);

    f32x4 acc[2][2][4][2];
#pragma unroll
    for (int i = 0; i < 2; ++i)
#pragma unroll
        for (int c = 0; c < 2; ++c)
#pragma unroll
            for (int mi = 0; mi < 4; ++mi)
#pragma unroll
                for (int ni = 0; ni < 2; ++ni) acc[i][c][mi][ni] = (f32x4){0.f, 0.f, 0.f, 0.f};
    float lsum[2][2][4];
#pragma unroll
    for (int i = 0; i < 2; ++i)
#pragma unroll
        for (int c = 0; c < 2; ++c)
#pragma unroll
            for (int mi = 0; mi < 4; ++mi) lsum[i][c][mi] = 0.f;

    for (int kc = 0; kc < 8; ++kc) {
        int s0 = kc * 32;
        // ---- V b-frags: one b128 load each (Vt is [d][s]) ----
        bf16x8 bfr[2][2][2];
#pragma unroll
        for (int i = 0; i < 2; ++i)
#pragma unroll
            for (int c = 0; c < 2; ++c)
#pragma unroll
                for (int ni = 0; ni < 2; ++ni)
                    bfr[i][c][ni] = *(const bf16x8*)(vtp[i][c] + (size_t)(ni * 16 + lrow) * 256 + s0 + quad * 8);
#pragma unroll
        for (int i = 0; i < 2; ++i) {
#pragma unroll
            for (int c = 0; c < 2; ++c) {
                f32x4 asv0 = *(const f32x4*)&as_l[i][c][wave][s0 + quad * 8];
                f32x4 asv1 = *(const f32x4*)&as_l[i][c][wave][s0 + quad * 8 + 4];
#pragma unroll
                for (int mi = 0; mi < 4; ++mi) {
                    unsigned wb = ml[i][c][kc][mi * 16 + lrow] >> (quad * 8);
                    float ad = ad_r[i][c][mi];
                    bf16x8 af;
#pragma unroll
                    for (int j = 0; j < 8; ++j) {
                        float u = (j < 4 ? asv0[j] : asv1[j - 4]) + ad;
                        u = fmaxf(u, 0.2f * u);           // leaky_relu (log2 domain)
                        u = ((wb >> j) & 1u) ? u : 0.f;   // masked -> exp2(0)=1
                        float e = fast_exp2(u);
                        lsum[i][c][mi] += e;
                        af[j] = (bf16)e;
                    }
                    acc[i][c][mi][0] = __builtin_amdgcn_mfma_f32_16x16x32_bf16(af, bfr[i][c][0], acc[i][c][mi][0], 0, 0, 0);
                    acc[i][c][mi][1] = __builtin_amdgcn_mfma_f32_16x16x32_bf16(af, bfr[i][c][1], acc[i][c][mi][1], 0, 0, 0);
                }
            }
        }
    }

    // ---- complete row sums across quads ----
#pragma unroll
    for (int i = 0; i < 2; ++i)
#pragma unroll
        for (int c = 0; c < 2; ++c)
#pragma unroll
            for (int mi = 0; mi < 4; ++mi) {
                float l = lsum[i][c][mi];
                l += __shfl_xor(l, 16, 64);
                l += __shfl_xor(l, 32, 64);
                if (lane < 16) l_lds[i][c][wave][mi * 16 + lane] = l;
            }
    __syncthreads();

    // ---- epilogue: normalize+residual+gbias per order, then mean+PReLU --------
#pragma unroll
    for (int ni = 0; ni < 2; ++ni) {
        int dcol = h * 32 + ni * 16 + lrow;
        float gb0 = gbias[0 * 256 + dcol] + gbias[1 * 256 + dcol];   // order 0
        float gb1 = gbias[2 * 256 + dcol] + gbias[3 * 256 + dcol];   // order 1
        float pa = prelu_a[dcol];
        const bf16* r00 = vtp[0][0] + (size_t)(ni * 16 + lrow) * 256 + t0;
        const bf16* r01 = vtp[0][1] + (size_t)(ni * 16 + lrow) * 256 + t0;
        const bf16* r10 = vtp[1][0] + (size_t)(ni * 16 + lrow) * 256 + t0;
        const bf16* r11 = vtp[1][1] + (size_t)(ni * 16 + lrow) * 256 + t0;
#pragma unroll
        for (int mi = 0; mi < 4; ++mi) {
            bf16x4 rv00 = *(const bf16x4*)(r00 + mi * 16 + quad * 4);
            bf16x4 rv01 = *(const bf16x4*)(r01 + mi * 16 + quad * 4);
            bf16x4 rv10 = *(const bf16x4*)(r10 + mi * 16 + quad * 4);
            bf16x4 rv11 = *(const bf16x4*)(r11 + mi * 16 + quad * 4);
#pragma unroll
            for (int r = 0; r < 4; ++r) {
                int tl = mi * 16 + quad * 4 + r;
                int t = t0 + tl;
                float v0 = acc[0][0][mi][ni][r] * __builtin_amdgcn_rcpf(l_lds[0][0][wave][tl])
                         + acc[0][1][mi][ni][r] * __builtin_amdgcn_rcpf(l_lds[0][1][wave][tl])
                         + (float)rv00[r] + (float)rv01[r] + gb0;
                float v1 = acc[1][0][mi][ni][r] * __builtin_amdgcn_rcpf(l_lds[1][0][wave][tl])
                         + acc[1][1][mi][ni][r] * __builtin_amdgcn_rcpf(l_lds[1][1][wave][tl])
                         + (float)rv10[r] + (float)rv11[r] + gb1;
                float mn = 0.5f * (v0 + v1);
                float a0 = v0 + mn, a1 = v1 + mn;
                a0 = a0 >= 0.f ? a0 : pa * a0;
                a1 = a1 >= 0.f ? a1 : pa * a1;
                out[(((size_t)((b * 2 + 0) * 256 + t)) << 8) + dcol] = a0;
                out[(((size_t)((b * 2 + 1) * 256 + t)) << 8) + dcol] = a1;
            }
        }
    }
}

extern "C" void kernel_launch(void* const* d_in, const int* in_sizes, int n_in,
                              void* d_out, int out_size, void* d_ws, size_t ws_size,
                              hipStream_t stream) {
    const float* x       = (const float*)d_in[0];
    const int*   A       = (const int*)d_in[1];
    const float* Wp      = (const float*)d_in[2];
    const float* bp      = (const float*)d_in[3];
    const float* att_src = (const float*)d_in[4];
    const float* att_dst = (const float*)d_in[5];
    const float* gbias   = (const float*)d_in[6];
    const float* prelu_a = (const float*)d_in[7];
    float* out = (float*)d_out;

    char* ws = (char*)d_ws;
    bf16*     Wt  = (bf16*)ws;                            //   524288 B
    unsigned* m1  = (unsigned*)(ws + 524288);             //  1048576 B
    unsigned* m2  = (unsigned*)(ws + 1572864);            //  1048576 B
    float*    asb = (float*)(ws + 2621440);               //  2097152 B
    float*    adb = (float*)(ws + 4718592);               //  2097152 B
    bf16*     xb  = (bf16*)(ws + 6815744);                // 16777216 B
    bf16*     Vt  = (bf16*)(ws + 23592960);               // 16777216 B

    prep_k<<<5376, 256, 0, stream>>>(x, Wp, A, xb, Wt, m1, m2);
    dim3 gproj(128, 4, 2);
    proj_gemm<<<gproj, 256, 0, stream>>>(xb, Wt, bp, att_src, att_dst, Vt, asb, adb);
    attn_k<<<512, 256, 0, stream>>>(Vt, m1, m2, asb, adb, gbias, prelu_a, out);
}

// Round 9
// 191.468 us; speedup vs baseline: 1.2106x; 1.1029x over previous
//
#include <hip/hip_runtime.h>
#include <hip/hip_bf16.h>
#include <math.h>

typedef __bf16 bf16;
typedef __bf16 bf16x4 __attribute__((ext_vector_type(4)));
typedef __bf16 bf16x8 __attribute__((ext_vector_type(8)));
typedef float f32x4 __attribute__((ext_vector_type(4)));
typedef unsigned int u32;

#define LOG2E 1.44269504f

__device__ inline float fast_exp2(float x) {
#if __has_builtin(__builtin_amdgcn_exp2f)
    return __builtin_amdgcn_exp2f(x);
#else
    return exp2f(x);
#endif
}

// async global->LDS, 16B per lane; LDS dest must be lane-contiguous (tid*16B)
#define GL2LDS(gp, lp) __builtin_amdgcn_global_load_lds( \
    (const __attribute__((address_space(1))) u32*)(gp),  \
    (__attribute__((address_space(3))) u32*)(lp), 16, 0, 0)

// Problem constants: B=64, ORDER=2, S=256, D=256, H=8, HD=32

// ---------------- kernel 1 (prologue): Wt bf16-transpose; A bitmasks -----------
// blocks [0,1024): W -> bf16 transposed. [1024,2048): pack A (block = ijb x kc).
__global__ void prep_k(const float* __restrict__ Wp, const int* __restrict__ A,
                       bf16* __restrict__ Wt, unsigned* __restrict__ m1,
                       unsigned* __restrict__ m2) {
    int bid = blockIdx.x;
    int tid = threadIdx.x;
    if (bid < 1024) {
        int gid = bid * 256 + tid;              // 4*256*256 elements
        int k = gid & 255;
        int n = (gid >> 8) & 255;
        int ij = gid >> 16;
        Wt[gid] = (bf16)Wp[(ij * 256 + k) * 256 + n];
    } else {
        int pb = bid - 1024;                    // 1024 = ijb*8 + kc
        int kc = pb & 7;
        int ijb = pb >> 3;                      // b*2+i
        const int* Ab = A + ((size_t)ijb << 16);
        unsigned w1 = 0, w2 = 0;
#pragma unroll
        for (int sl = 0; sl < 32; ++sl) {
            int s = kc * 32 + sl;
            int av = Ab[s * 256 + tid];
            unsigned f1 = (av == 2 || av == 4) ? 1u : 0u;
            unsigned f2 = (av == 3 || av == 4) ? 1u : 0u;
            w1 |= f1 << sl;
            w2 |= f2 << sl;
        }
        m1[(ijb * 8 + kc) * 256 + tid] = w1;
        m2[(ijb * 8 + kc) * 256 + tid] = w2;
    }
}

// ---------------- kernel 2: transposed projection GEMM + register scores ------
// Reads x fp32 DIRECTLY (no xb intermediate): A-tile staged via f32x4 load ->
// cvt -> padded ds_write_b128; B-tile (Wt, bf16) via global_load_lds.
// D[d][s] = (x@W+b)^T via swapped MFMA operands; Vt [ijb][h][d][s]; scores from
// acc registers, quad-reduced by shfl.
__launch_bounds__(256)
__global__ void proj_gemm(const float* __restrict__ x, const bf16* __restrict__ Wt,
                          const float* __restrict__ bp, const float* __restrict__ att_src,
                          const float* __restrict__ att_dst, bf16* __restrict__ Vt,
                          float* __restrict__ asb, float* __restrict__ adb) {
    __shared__ char smem[35840 + 1024];
    bf16* As = (bf16*)smem;             // x tile  [s 128][k stride 40] (padded)
    bf16* Bs = (bf16*)(smem + 10240);   // Wt tile [d 128][k 32] contiguous (GL2LDS)
    bf16* TL = (bf16*)smem;             // epilogue overlay: [d 128][s stride 140]
    float* attL = (float*)(smem + 35840);   // [which 2][dloc 128]

    int tid = threadIdx.x;
    int mt = blockIdx.x, nt = blockIdx.y, i = blockIdx.z;
    int n0 = nt * 128;
    int j = n0 >> 8, d0 = n0 & 255;
    int ij = i * 2 + j;
    int m0 = mt * 128;
    int b = m0 >> 8, shalf = (m0 >> 7) & 1;

    // preload att vectors for this block's 4 heads: attL[which][dloc]
    {
        int which = tid >> 7, rest = tid & 127;
        const float* ap = which ? att_dst : att_src;
        attL[tid] = ap[(ij * 8 + (d0 >> 5) + (rest >> 5)) * 32 + (rest & 31)];
    }

    // A staging: thread -> row mr = tid>>1, k-quarter kq = (tid&1)*16 (fp32 src)
    int mr = tid >> 1, kq = (tid & 1) * 16;
    const float* xrow = x + (((size_t)((b * 2 + i) * 256 + shalf * 128 + mr)) << 8) + kq;
    // B staging via GL2LDS: chunk c -> row c>>2, k-offset (c&3)*8, dest c*16B
    int c0 = tid, c1 = tid + 256;
    const bf16* gb0 = Wt + (((size_t)(ij * 256 + d0 + (c0 >> 2))) << 8) + (c0 & 3) * 8;
    const bf16* gb1 = Wt + (((size_t)(ij * 256 + d0 + (c1 >> 2))) << 8) + (c1 & 3) * 8;
    bf16* lb0 = Bs + c0 * 8;
    bf16* lb1 = Bs + c1 * 8;

    int wave = tid >> 6, lane = tid & 63;
    int wd = (wave & 1) * 64, ws = (wave >> 1) * 64;
    int lrow = lane & 15, quad = lane >> 4;

    f32x4 acc[4][4];   // [dj][sj]
#pragma unroll
    for (int a = 0; a < 4; ++a)
#pragma unroll
        for (int c = 0; c < 4; ++c) acc[a][c] = (f32x4){0.f, 0.f, 0.f, 0.f};

    for (int kc = 0; kc < 8; ++kc) {
        int k0 = kc * 32;
        GL2LDS(gb0 + k0, lb0);
        GL2LDS(gb1 + k0, lb1);
        {
            const float* ap = xrow + k0;
            f32x4 xa0 = *(const f32x4*)(ap);
            f32x4 xa1 = *(const f32x4*)(ap + 4);
            f32x4 xa2 = *(const f32x4*)(ap + 8);
            f32x4 xa3 = *(const f32x4*)(ap + 12);
            bf16x8 w0, w1;
#pragma unroll
            for (int q = 0; q < 4; ++q) {
                w0[q] = (bf16)xa0[q]; w0[q + 4] = (bf16)xa1[q];
                w1[q] = (bf16)xa2[q]; w1[q + 4] = (bf16)xa3[q];
            }
            *(bf16x8*)&As[mr * 40 + kq]     = w0;
            *(bf16x8*)&As[mr * 40 + kq + 8] = w1;
        }
        __syncthreads();
        bf16x8 wf[4], xf[4];
#pragma unroll
        for (int dj = 0; dj < 4; ++dj)
            wf[dj] = *(const bf16x8*)&Bs[(wd + dj * 16 + lrow) * 32 + quad * 8];
#pragma unroll
        for (int sj = 0; sj < 4; ++sj)
            xf[sj] = *(const bf16x8*)&As[(ws + sj * 16 + lrow) * 40 + quad * 8];
#pragma unroll
        for (int dj = 0; dj < 4; ++dj)
#pragma unroll
            for (int sj = 0; sj < 4; ++sj)
                acc[dj][sj] = __builtin_amdgcn_mfma_f32_16x16x32_bf16(wf[dj], xf[sj], acc[dj][sj], 0, 0, 0);
        __syncthreads();
    }

    // ---- bias + cvt -> TL[d][s] AND register score partials ----
    float sc[2][2][4];   // [which][head-half][sj]
#pragma unroll
    for (int w2 = 0; w2 < 2; ++w2)
#pragma unroll
        for (int hf = 0; hf < 2; ++hf)
#pragma unroll
            for (int sj = 0; sj < 4; ++sj) sc[w2][hf][sj] = 0.f;
#pragma unroll
    for (int dj = 0; dj < 4; ++dj) {
        int hf = dj >> 1;
#pragma unroll
        for (int r = 0; r < 4; ++r) {
            int dl = wd + dj * 16 + quad * 4 + r;
            float bias = bp[ij * 256 + d0 + dl];
            float avs = attL[dl];
            float avd = attL[128 + dl];
#pragma unroll
            for (int sj = 0; sj < 4; ++sj) {
                float v = acc[dj][sj][r] + bias;
                TL[dl * 140 + ws + sj * 16 + lrow] = (bf16)v;
                sc[0][hf][sj] += v * avs;
                sc[1][hf][sj] += v * avd;
            }
        }
    }
    // quad-reduce the score partials (d-range of a head spans the 4 quads)
#pragma unroll
    for (int w2 = 0; w2 < 2; ++w2)
#pragma unroll
        for (int hf = 0; hf < 2; ++hf)
#pragma unroll
            for (int sj = 0; sj < 4; ++sj) {
                float v = sc[w2][hf][sj];
                v += __shfl_xor(v, 16, 64);
                v += __shfl_xor(v, 32, 64);
                sc[w2][hf][sj] = v;
            }
    if (lane < 16) {
        int hbase = (d0 >> 5) + (wd >> 5);   // wd>>5 in {0,2}
#pragma unroll
        for (int w2 = 0; w2 < 2; ++w2) {
            float* outp = w2 ? adb : asb;
#pragma unroll
            for (int hf = 0; hf < 2; ++hf) {
                int hh = hbase + hf;
#pragma unroll
                for (int sj = 0; sj < 4; ++sj) {
                    int s = ws + sj * 16 + lane;
                    outp[((ij * 64 + b) * 8 + hh) * 256 + shalf * 128 + s] = sc[w2][hf][sj] * LOG2E;
                }
            }
        }
    }
    __syncthreads();

    // ---- Vt store: thread -> (dl = tid>>1, s-half 64) ----
    {
        int dl = tid >> 1, sh64 = (tid & 1) * 64;
        const bf16* src = TL + dl * 140 + sh64;
        bf16* dst = Vt + (((size_t)(ij * 64 + b)) << 16) + (size_t)(d0 + dl) * 256
                    + shalf * 128 + sh64;   // slab per (ij,b) = 8h*32d*256s = <<16
#pragma unroll
        for (int q = 0; q < 16; ++q)
            *(bf16x4*)(dst + q * 4) = *(const bf16x4*)(src + q * 4);
    }
}

// ---------------- kernel 3: fused attention + order-mean + PReLU ---------------
// grid 1024: (b, head-group of 4, t-tile of 32); block owns both orders + convs.
// XCD swizzle: low 3 bits of bid = b%8 (8 b's x 256 KB = 2 MB per XCD L2).
__launch_bounds__(256, 3)
__global__ void attn_k(const bf16* __restrict__ Vt, const unsigned* __restrict__ m1,
                       const unsigned* __restrict__ m2, const float* __restrict__ asb,
                       const float* __restrict__ adb, const float* __restrict__ gbias,
                       const float* __restrict__ prelu_a, float* __restrict__ out) {
    int bid = blockIdx.x;
    int blow = bid & 7;
    int rest = bid >> 3;
    int tt = rest & 7, hg = (rest >> 3) & 1, b = (rest >> 4) * 8 + blow;
    int t0 = tt * 32;
    int tid = threadIdx.x, wave = tid >> 6, lane = tid & 63;
    int lrow = lane & 15, quad = lane >> 4;
    int h = hg * 4 + wave;

    __shared__ float    as_l[2][2][4][256];   // [i][conv][wave-head][s]   16 KB
    __shared__ unsigned ml[2][2][8][32];      // [i][conv][kc][t_local]     4 KB
    __shared__ float    l_lds[2][2][4][32];   // [i][conv][wave-head][tl]   2 KB

#pragma unroll
    for (int p = 0; p < 16; ++p) {
        int idx = p * 256 + tid;
        int i = idx >> 11, c = (idx >> 10) & 1, w = (idx >> 8) & 3, s = idx & 255;
        as_l[i][c][w][s] = asb[(((i * 2 + c) * 64 + b) * 8 + hg * 4 + w) * 256 + s];
    }
#pragma unroll
    for (int p = 0; p < 4; ++p) {
        int idx = p * 256 + tid;            // 1024 mask words
        int i = idx >> 9, c = (idx >> 8) & 1, kc = (idx >> 5) & 7, tl = idx & 31;
        ml[i][c][kc][tl] = (c ? m2 : m1)[((b * 2 + i) * 8 + kc) * 256 + t0 + tl];
    }
    float ad_r[2][2][2];
#pragma unroll
    for (int i = 0; i < 2; ++i)
#pragma unroll
        for (int c = 0; c < 2; ++c)
#pragma unroll
            for (int mi = 0; mi < 2; ++mi)
                ad_r[i][c][mi] = adb[(((i * 2 + c) * 64 + b) * 8 + h) * 256 + t0 + mi * 16 + lrow];
    __syncthreads();

    const bf16* vtp[2][2];
#pragma unroll
    for (int i = 0; i < 2; ++i)
#pragma unroll
        for (int c = 0; c < 2; ++c)
            vtp[i][c] = Vt + (((size_t)(((i * 2 + c) * 64 + b) * 8 + h)) << 13);

    f32x4 acc[2][2][2][2];
#pragma unroll
    for (int i = 0; i < 2; ++i)
#pragma unroll
        for (int c = 0; c < 2; ++c)
#pragma unroll
            for (int mi = 0; mi < 2; ++mi)
#pragma unroll
                for (int ni = 0; ni < 2; ++ni) acc[i][c][mi][ni] = (f32x4){0.f, 0.f, 0.f, 0.f};
    float lsum[2][2][2];
#pragma unroll
    for (int i = 0; i < 2; ++i)
#pragma unroll
        for (int c = 0; c < 2; ++c)
#pragma unroll
            for (int mi = 0; mi < 2; ++mi) lsum[i][c][mi] = 0.f;

    for (int kc = 0; kc < 8; ++kc) {
        int s0 = kc * 32;
        // ---- V b-frags: one b128 load each (Vt is [d][s]) ----
        bf16x8 bfr[2][2][2];
#pragma unroll
        for (int i = 0; i < 2; ++i)
#pragma unroll
            for (int c = 0; c < 2; ++c)
#pragma unroll
                for (int ni = 0; ni < 2; ++ni)
                    bfr[i][c][ni] = *(const bf16x8*)(vtp[i][c] + (size_t)(ni * 16 + lrow) * 256 + s0 + quad * 8);
#pragma unroll
        for (int i = 0; i < 2; ++i) {
#pragma unroll
            for (int c = 0; c < 2; ++c) {
                f32x4 asv0 = *(const f32x4*)&as_l[i][c][wave][s0 + quad * 8];
                f32x4 asv1 = *(const f32x4*)&as_l[i][c][wave][s0 + quad * 8 + 4];
#pragma unroll
                for (int mi = 0; mi < 2; ++mi) {
                    unsigned wb = ml[i][c][kc][mi * 16 + lrow] >> (quad * 8);
                    float ad = ad_r[i][c][mi];
                    bf16x8 af;
#pragma unroll
                    for (int j = 0; j < 8; ++j) {
                        float u = (j < 4 ? asv0[j] : asv1[j - 4]) + ad;
                        u = fmaxf(u, 0.2f * u);           // leaky_relu (log2 domain)
                        u = ((wb >> j) & 1u) ? u : 0.f;   // masked -> exp2(0)=1
                        float e = fast_exp2(u);
                        lsum[i][c][mi] += e;
                        af[j] = (bf16)e;
                    }
                    acc[i][c][mi][0] = __builtin_amdgcn_mfma_f32_16x16x32_bf16(af, bfr[i][c][0], acc[i][c][mi][0], 0, 0, 0);
                    acc[i][c][mi][1] = __builtin_amdgcn_mfma_f32_16x16x32_bf16(af, bfr[i][c][1], acc[i][c][mi][1], 0, 0, 0);
                }
            }
        }
    }

    // ---- complete row sums across quads ----
#pragma unroll
    for (int i = 0; i < 2; ++i)
#pragma unroll
        for (int c = 0; c < 2; ++c)
#pragma unroll
            for (int mi = 0; mi < 2; ++mi) {
                float l = lsum[i][c][mi];
                l += __shfl_xor(l, 16, 64);
                l += __shfl_xor(l, 32, 64);
                if (lane < 16) l_lds[i][c][wave][mi * 16 + lane] = l;
            }
    __syncthreads();

    // ---- epilogue: normalize+residual+gbias per order, then mean+PReLU --------
#pragma unroll
    for (int ni = 0; ni < 2; ++ni) {
        int dcol = h * 32 + ni * 16 + lrow;
        float gb0 = gbias[0 * 256 + dcol] + gbias[1 * 256 + dcol];   // order 0
        float gb1 = gbias[2 * 256 + dcol] + gbias[3 * 256 + dcol];   // order 1
        float pa = prelu_a[dcol];
        const bf16* r00 = vtp[0][0] + (size_t)(ni * 16 + lrow) * 256 + t0;
        const bf16* r01 = vtp[0][1] + (size_t)(ni * 16 + lrow) * 256 + t0;
        const bf16* r10 = vtp[1][0] + (size_t)(ni * 16 + lrow) * 256 + t0;
        const bf16* r11 = vtp[1][1] + (size_t)(ni * 16 + lrow) * 256 + t0;
#pragma unroll
        for (int mi = 0; mi < 2; ++mi) {
            bf16x4 rv00 = *(const bf16x4*)(r00 + mi * 16 + quad * 4);
            bf16x4 rv01 = *(const bf16x4*)(r01 + mi * 16 + quad * 4);
            bf16x4 rv10 = *(const bf16x4*)(r10 + mi * 16 + quad * 4);
            bf16x4 rv11 = *(const bf16x4*)(r11 + mi * 16 + quad * 4);
#pragma unroll
            for (int r = 0; r < 4; ++r) {
                int tl = mi * 16 + quad * 4 + r;
                int t = t0 + tl;
                float v0 = acc[0][0][mi][ni][r] * __builtin_amdgcn_rcpf(l_lds[0][0][wave][tl])
                         + acc[0][1][mi][ni][r] * __builtin_amdgcn_rcpf(l_lds[0][1][wave][tl])
                         + (float)rv00[r] + (float)rv01[r] + gb0;
                float v1 = acc[1][0][mi][ni][r] * __builtin_amdgcn_rcpf(l_lds[1][0][wave][tl])
                         + acc[1][1][mi][ni][r] * __builtin_amdgcn_rcpf(l_lds[1][1][wave][tl])
                         + (float)rv10[r] + (float)rv11[r] + gb1;
                float mn = 0.5f * (v0 + v1);
                float a0 = v0 + mn, a1 = v1 + mn;
                a0 = a0 >= 0.f ? a0 : pa * a0;
                a1 = a1 >= 0.f ? a1 : pa * a1;
                out[(((size_t)((b * 2 + 0) * 256 + t)) << 8) + dcol] = a0;
                out[(((size_t)((b * 2 + 1) * 256 + t)) << 8) + dcol] = a1;
            }
        }
    }
}

extern "C" void kernel_launch(void* const* d_in, const int* in_sizes, int n_in,
                              void* d_out, int out_size, void* d_ws, size_t ws_size,
                              hipStream_t stream) {
    const float* x       = (const float*)d_in[0];
    const int*   A       = (const int*)d_in[1];
    const float* Wp      = (const float*)d_in[2];
    const float* bp      = (const float*)d_in[3];
    const float* att_src = (const float*)d_in[4];
    const float* att_dst = (const float*)d_in[5];
    const float* gbias   = (const float*)d_in[6];
    const float* prelu_a = (const float*)d_in[7];
    float* out = (float*)d_out;

    char* ws = (char*)d_ws;
    bf16*     Wt  = (bf16*)ws;                            //   524288 B
    unsigned* m1  = (unsigned*)(ws + 524288);             //  1048576 B
    unsigned* m2  = (unsigned*)(ws + 1572864);            //  1048576 B
    float*    asb = (float*)(ws + 2621440);               //  2097152 B
    float*    adb = (float*)(ws + 4718592);               //  2097152 B
    bf16*     Vt  = (bf16*)(ws + 6815744);                // 16777216 B

    prep_k<<<2048, 256, 0, stream>>>(Wp, A, Wt, m1, m2);
    dim3 gproj(128, 4, 2);
    proj_gemm<<<gproj, 256, 0, stream>>>(x, Wt, bp, att_src, att_dst, Vt, asb, adb);
    attn_k<<<1024, 256, 0, stream>>>(Vt, m1, m2, asb, adb, gbias, prelu_a, out);
}